// Round 7
// baseline (184.233 us; speedup 1.0000x reference)
//
#include <hip/hip_runtime.h>
#include <math.h>

#define EPS 1e-4f
#define QAM_NORM 0.31622776601683794f  // 1/sqrt(10)
#define RCP(x) __builtin_amdgcn_rcpf(x)

// FOUR lanes per site. Lane g owns antennas {g,g+4,g+8,g+12} and stream k=g.
// Restructured math vs R6:
//  - Kt dropped entirely (cancels in lse1-lse0)
//  - err_var closed form: ev = E|p|^2 - |s|^2  (EPS-clamp delta <= 1e-8)
//  - A = M*diag(ev), M = G + no*diag(1/ev) Hermitian -> LDL^H factor +
//    one solve (M^-1 resid) + diag(M^-1) via L^-1; replaces full GJ inverse.
//  - all divides via v_rcp_f32; branchless sigmoid.
// No min-waves launch bound (R3/R4: forcing causes catastrophic spills).
__global__ __launch_bounds__(256) void siso_pic_kernel(
    const float* __restrict__ y,     // (S,16,2)
    const float* __restrict__ h,     // (S,16,4,2)
    const float* __restrict__ llr_a, // (S,4,4)
    const float* __restrict__ no_p,  // (1,)
    float* __restrict__ out,         // (S,4,4)
    int nsites)
{
    int tid = blockIdx.x * blockDim.x + threadIdx.x;
    int site = tid >> 2;
    int g = tid & 3;
    if (site >= nsites) return;
    int gb = (threadIdx.x & 63) & ~3;     // 4-lane group base within wave
    const float no = no_p[0];

    // ---- phase 1: partial G (diag Gd, upper pairs Gu), y_mf over 4 antennas ----
    // pair order p: (0,1),(0,2),(0,3),(1,2),(1,3),(2,3)
    const int PI[6] = {0,0,0,1,1,2};
    const int PJ[6] = {1,2,3,2,3,3};
    float Gd[4] = {0.f,0.f,0.f,0.f};
    float Gur[6] = {0.f,0.f,0.f,0.f,0.f,0.f};
    float Gui[6] = {0.f,0.f,0.f,0.f,0.f,0.f};
    float ymr[4] = {0.f,0.f,0.f,0.f};
    float ymi[4] = {0.f,0.f,0.f,0.f};
    const float4* hp = reinterpret_cast<const float4*>(h + (size_t)site * 128);
    const float2* yp = reinterpret_cast<const float2*>(y + (size_t)site * 32);
    #pragma unroll
    for (int mm = 0; mm < 4; mm++) {
        int m = 4 * mm + g;
        float4 hA = hp[2 * m];
        float4 hB = hp[2 * m + 1];
        float2 yv = yp[m];
        float hre[4] = {hA.x, hA.z, hB.x, hB.z};
        float him[4] = {hA.y, hA.w, hB.y, hB.w};
        #pragma unroll
        for (int i = 0; i < 4; i++) {
            ymr[i] += hre[i] * yv.x + him[i] * yv.y;
            ymi[i] += hre[i] * yv.y - him[i] * yv.x;
            Gd[i]  += hre[i] * hre[i] + him[i] * him[i];
        }
        #pragma unroll
        for (int p = 0; p < 6; p++) {
            int i = PI[p], j = PJ[p];
            Gur[p] += hre[i] * hre[j] + him[i] * him[j];
            Gui[p] += hre[i] * him[j] - him[i] * hre[j];
        }
    }
    // butterfly reduce 24 values across the 4-lane group
    #pragma unroll
    for (int i = 0; i < 4; i++) {
        ymr[i] += __shfl_xor(ymr[i], 1); ymr[i] += __shfl_xor(ymr[i], 2);
        ymi[i] += __shfl_xor(ymi[i], 1); ymi[i] += __shfl_xor(ymi[i], 2);
        Gd[i]  += __shfl_xor(Gd[i],  1); Gd[i]  += __shfl_xor(Gd[i],  2);
    }
    #pragma unroll
    for (int p = 0; p < 6; p++) {
        Gur[p] += __shfl_xor(Gur[p], 1); Gur[p] += __shfl_xor(Gur[p], 2);
        Gui[p] += __shfl_xor(Gui[p], 1); Gui[p] += __shfl_xor(Gui[p], 2);
    }

    // ---- phase 2: own-stream prior -> sh, ev (closed forms) --------------------
    const float4 lv = reinterpret_cast<const float4*>(llr_a + (size_t)site * 16)[g];
    float p00 = RCP(1.f + __expf(lv.x));   // sigmoid(-x) = 0.5*(1-tanh(x/2))
    float p01 = RCP(1.f + __expf(lv.y));
    float p02 = RCP(1.f + __expf(lv.z));
    float p03 = RCP(1.f + __expf(lv.w));
    float t0 = 2.f * p00 - 1.f, t1 = 2.f * p01 - 1.f;
    float t2 = 2.f * p02 - 1.f, t3 = 2.f * p03 - 1.f;
    float shr_own = QAM_NORM * t0 * (2.f - t2);
    float shi_own = QAM_NORM * t1 * (2.f - t3);
    // E|p|^2 = (18 - 8*(p0_2+p0_3))/10 ; ev = E|p|^2 - |s|^2
    float ev_own = 0.1f * (18.f - 8.f * (p02 + p03))
                 - (shr_own * shr_own + shi_own * shi_own);
    ev_own = fmaxf(ev_own, 1e-8f);
    float evinv_own = RCP(ev_own);

    // gather sh[4], evinv[4] from the group
    float shr4[4], shi4[4], evi4[4];
    #pragma unroll
    for (int j = 0; j < 4; j++) {
        shr4[j] = __shfl(shr_own, gb + j);
        shi4[j] = __shfl(shi_own, gb + j);
        evi4[j] = __shfl(evinv_own, gb + j);
    }

    // ---- phase 3: resid = ymf - G*sh (explicit Hermitian matvec) ---------------
    float r0r = ymr[0] - (Gd[0]*shr4[0] + (Gur[0]*shr4[1] - Gui[0]*shi4[1])
                        + (Gur[1]*shr4[2] - Gui[1]*shi4[2]) + (Gur[2]*shr4[3] - Gui[2]*shi4[3]));
    float r0i = ymi[0] - (Gd[0]*shi4[0] + (Gur[0]*shi4[1] + Gui[0]*shr4[1])
                        + (Gur[1]*shi4[2] + Gui[1]*shr4[2]) + (Gur[2]*shi4[3] + Gui[2]*shr4[3]));
    float r1r = ymr[1] - ((Gur[0]*shr4[0] + Gui[0]*shi4[0]) + Gd[1]*shr4[1]
                        + (Gur[3]*shr4[2] - Gui[3]*shi4[2]) + (Gur[4]*shr4[3] - Gui[4]*shi4[3]));
    float r1i = ymi[1] - ((Gur[0]*shi4[0] - Gui[0]*shr4[0]) + Gd[1]*shi4[1]
                        + (Gur[3]*shi4[2] + Gui[3]*shr4[2]) + (Gur[4]*shi4[3] + Gui[4]*shr4[3]));
    float r2r = ymr[2] - ((Gur[1]*shr4[0] + Gui[1]*shi4[0]) + (Gur[3]*shr4[1] + Gui[3]*shi4[1])
                        + Gd[2]*shr4[2] + (Gur[5]*shr4[3] - Gui[5]*shi4[3]));
    float r2i = ymi[2] - ((Gur[1]*shi4[0] - Gui[1]*shr4[0]) + (Gur[3]*shi4[1] - Gui[3]*shr4[1])
                        + Gd[2]*shi4[2] + (Gur[5]*shi4[3] + Gui[5]*shr4[3]));
    float r3r = ymr[3] - ((Gur[2]*shr4[0] + Gui[2]*shi4[0]) + (Gur[4]*shr4[1] + Gui[4]*shi4[1])
                        + (Gur[5]*shr4[2] + Gui[5]*shi4[2]) + Gd[3]*shr4[3]);
    float r3i = ymi[3] - ((Gur[2]*shi4[0] - Gui[2]*shr4[0]) + (Gur[4]*shi4[1] - Gui[4]*shr4[1])
                        + (Gur[5]*shi4[2] - Gui[5]*shr4[2]) + Gd[3]*shi4[3]);

    // ---- phase 4: M = G + no*diag(1/ev) ; LDL^H factor -------------------------
    float Md0 = Gd[0] + no * evi4[0];
    float Md1 = Gd[1] + no * evi4[1];
    float Md2 = Gd[2] + no * evi4[2];
    float Md3 = Gd[3] + no * evi4[3];
    // lower entries M_ik = conj(Gu): (Gur[p], -Gui[p])
    float d0 = Md0;                    float i0 = RCP(d0);
    float L10r =  Gur[0]*i0, L10i = -Gui[0]*i0;
    float L20r =  Gur[1]*i0, L20i = -Gui[1]*i0;
    float L30r =  Gur[2]*i0, L30i = -Gui[2]*i0;
    float d1 = Md1 - (L10r*L10r + L10i*L10i)*d0;   float i1 = RCP(d1);
    float e21r = L20r*L10r + L20i*L10i, e21i = L20i*L10r - L20r*L10i;  // L20*conj(L10)
    float L21r = ( Gur[3] - e21r*d0)*i1, L21i = (-Gui[3] - e21i*d0)*i1;
    float e31r = L30r*L10r + L30i*L10i, e31i = L30i*L10r - L30r*L10i;  // L30*conj(L10)
    float L31r = ( Gur[4] - e31r*d0)*i1, L31i = (-Gui[4] - e31i*d0)*i1;
    float d2 = Md2 - (L20r*L20r + L20i*L20i)*d0 - (L21r*L21r + L21i*L21i)*d1;
    float i2 = RCP(d2);
    float e32r = L30r*L20r + L30i*L20i, e32i = L30i*L20r - L30r*L20i;  // L30*conj(L20)
    float f32r = L31r*L21r + L31i*L21i, f32i = L31i*L21r - L31r*L21i;  // L31*conj(L21)
    float L32r = ( Gur[5] - e32r*d0 - f32r*d1)*i2;
    float L32i = (-Gui[5] - e32i*d0 - f32i*d1)*i2;
    float d3 = Md3 - (L30r*L30r + L30i*L30i)*d0 - (L31r*L31r + L31i*L31i)*d1
                   - (L32r*L32r + L32i*L32i)*d2;
    float i3 = RCP(d3);

    // ---- phase 5: solve M u = resid (fwd, scale, bwd) --------------------------
    float c0r = r0r, c0i = r0i;
    float c1r = r1r - (L10r*c0r - L10i*c0i);
    float c1i = r1i - (L10r*c0i + L10i*c0r);
    float c2r = r2r - (L20r*c0r - L20i*c0i) - (L21r*c1r - L21i*c1i);
    float c2i = r2i - (L20r*c0i + L20i*c0r) - (L21r*c1i + L21i*c1r);
    float c3r = r3r - (L30r*c0r - L30i*c0i) - (L31r*c1r - L31i*c1i) - (L32r*c2r - L32i*c2i);
    float c3i = r3i - (L30r*c0i + L30i*c0r) - (L31r*c1i + L31i*c1r) - (L32r*c2i + L32i*c2r);
    float u3r = c3r*i3, u3i = c3i*i3;
    float u2r = c2r*i2 - (L32r*u3r + L32i*u3i);            // conj(L32)*u3
    float u2i = c2i*i2 - (L32r*u3i - L32i*u3r);
    float u1r = c1r*i1 - (L21r*u2r + L21i*u2i) - (L31r*u3r + L31i*u3i);
    float u1i = c1i*i1 - (L21r*u2i - L21i*u2r) - (L31r*u3i - L31i*u3r);
    float u0r = c0r*i0 - (L10r*u1r + L10i*u1i) - (L20r*u2r + L20i*u2i) - (L30r*u3r + L30i*u3i);
    float u0i = c0i*i0 - (L10r*u1i - L10i*u1r) - (L20r*u2i - L20i*u2r) - (L30r*u3i - L30i*u3r);

    // ---- phase 6: diag(M^-1) via N = L^-1 --------------------------------------
    float N20r = (L21r*L10r - L21i*L10i) - L20r;
    float N20i = (L21r*L10i + L21i*L10r) - L20i;
    float N31r = (L32r*L21r - L32i*L21i) - L31r;
    float N31i = (L32r*L21i + L32i*L21r) - L31i;
    float ar_ = L31r*L10r - L31i*L10i, ai_ = L31r*L10i + L31i*L10r;   // L31*L10
    float br_ = L32r*N20r - L32i*N20i, bi_ = L32r*N20i + L32i*N20r;   // L32*N20
    float N30r = ar_ - br_ - L30r;
    float N30i = ai_ - bi_ - L30i;
    float q0 = i0 + (L10r*L10r + L10i*L10i)*i1 + (N20r*N20r + N20i*N20i)*i2
                  + (N30r*N30r + N30i*N30i)*i3;
    float q1 = i1 + (L21r*L21r + L21i*L21i)*i2 + (N31r*N31r + N31i*N31i)*i3;
    float q2 = i2 + (L32r*L32r + L32i*L32i)*i3;
    float q3 = i3;

    // own entries
    float ur = (g == 0) ? u0r : (g == 1) ? u1r : (g == 2) ? u2r : u3r;
    float ui = (g == 0) ? u0i : (g == 1) ? u1i : (g == 2) ? u2i : u3i;
    float qq = (g == 0) ? q0  : (g == 1) ? q1  : (g == 2) ? q2  : q3;

    // ---- phase 7: mu, z, rho ---------------------------------------------------
    // mu_k = (1 - no*(M^-1)_kk/ev_k)/ev_k  [= Re(diag(A^-1 G))_kk]
    float m = fmaxf((1.f - no * qq * evinv_own) * evinv_own, EPS);
    float rmu = RCP(m);
    float zr = ur * evinv_own * rmu + shr_own;   // (A^-1 r)_k / mu + sh
    float zi = ui * evinv_own * rmu + shi_own;
    float rh = m * RCP(fmaxf(1.f - ev_own * m, EPS));

    // ---- phase 8: exponents + per-bit logsumexp (own stream; Kt cancels) -------
    float l0 = lv.x, l1 = lv.y, l2 = lv.z, l3 = lv.w;
    float dA[4] = { -0.5f*(l0+l1), -0.5f*(l0-l1), 0.5f*(l0-l1), 0.5f*(l0+l1) };
    float dB[4] = { -0.5f*(l2+l3), -0.5f*(l2-l3), 0.5f*(l2-l3), 0.5f*(l2+l3) };
    float ex[16];
    #pragma unroll
    for (int i = 0; i < 16; i++) {
        int b0 = (i >> 3) & 1, b1 = (i >> 2) & 1, b2 = (i >> 1) & 1, b3 = i & 1;
        float pr = (float)((1 - 2*b0) * (1 + 2*b2)) * QAM_NORM;
        float pi = (float)((1 - 2*b1) * (1 + 2*b3)) * QAM_NORM;
        float dr = zr - pr, di = zi - pi;
        float d2 = fmaxf(dr*dr + di*di, EPS*EPS);
        ex[i] = -d2 * rh + dA[(b0<<1)|b1] + dB[(b2<<1)|b3];
    }
    float res[4];
    #pragma unroll
    for (int j = 0; j < 4; j++) {
        // gather the two 8-element groups (bit (3-j) of i)
        float e1[8], e0[8];
        int n1 = 0, n0 = 0;
        #pragma unroll
        for (int i = 0; i < 16; i++) {
            if ((i >> (3 - j)) & 1) e1[n1++] = ex[i];
            else                    e0[n0++] = ex[i];
        }
        float m1 = fmaxf(fmaxf(fmaxf(e1[0],e1[1]), fmaxf(e1[2],e1[3])),
                         fmaxf(fmaxf(e1[4],e1[5]), fmaxf(e1[6],e1[7])));
        float m0 = fmaxf(fmaxf(fmaxf(e0[0],e0[1]), fmaxf(e0[2],e0[3])),
                         fmaxf(fmaxf(e0[4],e0[5]), fmaxf(e0[6],e0[7])));
        float s1 = __expf(e1[0]-m1) + __expf(e1[1]-m1) + __expf(e1[2]-m1) + __expf(e1[3]-m1)
                 + __expf(e1[4]-m1) + __expf(e1[5]-m1) + __expf(e1[6]-m1) + __expf(e1[7]-m1);
        float s0 = __expf(e0[0]-m0) + __expf(e0[1]-m0) + __expf(e0[2]-m0) + __expf(e0[3]-m0)
                 + __expf(e0[4]-m0) + __expf(e0[5]-m0) + __expf(e0[6]-m0) + __expf(e0[7]-m0);
        res[j] = (m1 - m0) + (__logf(s1) - __logf(s0));
    }
    reinterpret_cast<float4*>(out + (size_t)site * 16)[g] =
        make_float4(res[0], res[1], res[2], res[3]);
}

extern "C" void kernel_launch(void* const* d_in, const int* in_sizes, int n_in,
                              void* d_out, int out_size, void* d_ws, size_t ws_size,
                              hipStream_t stream) {
    const float* y    = (const float*)d_in[0];
    const float* h    = (const float*)d_in[1];
    const float* llr  = (const float*)d_in[2];
    const float* no   = (const float*)d_in[3];
    float* out = (float*)d_out;
    int nsites = in_sizes[2] / 16;   // B*T*S = 196608
    int threads = 256;
    long long total = 4LL * nsites;  // 4 lanes per site
    int blocks = (int)((total + threads - 1) / threads);
    siso_pic_kernel<<<blocks, threads, 0, stream>>>(y, h, llr, no, out, nsites);
}